// Round 12
// baseline (443.878 us; speedup 1.0000x reference)
//
#include <hip/hip_runtime.h>
#include <cmath>

typedef __attribute__((ext_vector_type(8))) short bf16x8;
typedef __attribute__((ext_vector_type(4))) float f32x4;
typedef __attribute__((ext_vector_type(4))) unsigned short u16x4;
typedef __attribute__((ext_vector_type(8))) unsigned short u16x8;
typedef unsigned short u16;

#define ATTN_SCALE 0.25f

__device__ inline u16 f2bf(float x) {
    union { float f; unsigned u; } v; v.f = x;
    unsigned r = v.u + 0x7FFFu + ((v.u >> 16) & 1u);
    return (u16)(r >> 16);
}
__device__ inline float bf2f(u16 u) {
    union { unsigned u; float f; } v; v.u = ((unsigned)u) << 16; return v.f;
}
__device__ inline float fast_tanh(float x) {
    float xc = fminf(fmaxf(x, -15.f), 15.f);
    float t = __expf(2.f * xc);
    return (t - 1.f) * __builtin_amdgcn_rcpf(t + 1.f);
}

// ---------- CSR build ----------

__global__ __launch_bounds__(256) void hist_kernel(const int* __restrict__ dst,
                                                   int* __restrict__ counts, int E) {
    int i = blockIdx.x * 256 + threadIdx.x;
    if (i < E) atomicAdd(&counts[dst[i]], 1);
}

__global__ __launch_bounds__(256) void scan1(const int* __restrict__ counts,
                                             int* __restrict__ tmp, int* __restrict__ bsum, int N) {
    __shared__ int wsum[4];
    int b = blockIdx.x, t = threadIdx.x;
    int base = b * 1024 + t * 4;
    int v0 = (base + 0 < N) ? counts[base + 0] : 0;
    int v1 = (base + 1 < N) ? counts[base + 1] : 0;
    int v2 = (base + 2 < N) ? counts[base + 2] : 0;
    int v3 = (base + 3 < N) ? counts[base + 3] : 0;
    int p0 = v0, p1 = p0 + v1, p2 = p1 + v2, p3 = p2 + v3;
    int s = p3;
    int lane = t & 63, wid = t >> 6;
    int sc = s;
    #pragma unroll
    for (int d = 1; d < 64; d <<= 1) {
        int o = __shfl_up(sc, d);
        if (lane >= d) sc += o;
    }
    if (lane == 63) wsum[wid] = sc;
    __syncthreads();
    int wof = 0;
    #pragma unroll
    for (int i = 0; i < 4; ++i) if (i < wid) wof += wsum[i];
    int excl = wof + sc - s;
    if (base + 0 < N) tmp[base + 0] = excl + p0;
    if (base + 1 < N) tmp[base + 1] = excl + p1;
    if (base + 2 < N) tmp[base + 2] = excl + p2;
    if (base + 3 < N) tmp[base + 3] = excl + p3;
    if (t == 255) bsum[b] = wof + sc;
}

__global__ void scan2(int* __restrict__ bsum, int nb) {
    int t = threadIdx.x;
    int v = (t < nb) ? bsum[t] : 0;
    int sc = v;
    #pragma unroll
    for (int d = 1; d < 64; d <<= 1) {
        int o = __shfl_up(sc, d);
        if (t >= d) sc += o;
    }
    if (t < nb) bsum[t] = sc - v;
}

__global__ __launch_bounds__(256) void scan3(const int* __restrict__ tmp,
                                             const int* __restrict__ bsum,
                                             int* __restrict__ offsets,
                                             int* __restrict__ cursor, int N) {
    int i = blockIdx.x * 256 + threadIdx.x;
    if (i < N) {
        int v = tmp[i] + bsum[i >> 10];
        offsets[i + 1] = v;
        cursor[i + 1] = v;
    }
    if (i == 0) { offsets[0] = 0; cursor[0] = 0; }
}

__global__ __launch_bounds__(256) void scatter_kernel(const int* __restrict__ dst,
                                                      int* __restrict__ cursor,
                                                      int* __restrict__ eidx, int E) {
    int i = blockIdx.x * 256 + threadIdx.x;
    if (i < E) {
        int p = atomicAdd(&cursor[dst[i]], 1);
        eidx[p] = i;
    }
}

// ---------- 6 weight matrices -> MFMA B-fragments in ONE launch ----------
__global__ __launch_bounds__(256) void make_frag6(
    const float* __restrict__ w0, const float* __restrict__ w1,
    const float* __restrict__ w2, const float* __restrict__ w3,
    const float* __restrict__ w4, const float* __restrict__ w5,
    short* __restrict__ out) {
    int m = blockIdx.x >> 3;
    int id = (blockIdx.x & 7) * 256 + threadIdx.x;
    const float* W = (m == 0) ? w0 : (m == 1) ? w1 : (m == 2) ? w2
                   : (m == 3) ? w3 : (m == 4) ? w4 : w5;
    int l = id & 63, t16 = id >> 6;
    int kk = t16 & 3, n = t16 >> 2;
    int col = n * 16 + (l & 15);
    int k0 = kk * 32 + (l >> 4) * 8;
    short* o = out + (size_t)m * 2048 * 8 + (size_t)id * 8;
    #pragma unroll
    for (int j = 0; j < 8; ++j)
        o[j] = (short)f2bf(W[col * 128 + k0 + j]);
}

// ---------- qkv GEMM: BARRIER-FREE, no LDS ----------

__global__ __launch_bounds__(256) void qkv_gemm(
    const float* __restrict__ X, const short* __restrict__ frag,
    const float* __restrict__ bias,
    u16* __restrict__ Yq, u16* __restrict__ Yk, u16* __restrict__ Yv, int R)
{
    const int t = threadIdx.x;
    const int base = blockIdx.x * 64;
    const int w = t >> 6, l = t & 63, lr = l & 15, lg = l >> 4;

    const int myrow = base + w * 16 + lr;
    const float* xrow = X + (size_t)(myrow < R ? myrow : (R - 1)) * 128;
    bf16x8 afr[4];
    #pragma unroll
    for (int kk = 0; kk < 4; ++kk) {
        float4 f0 = *reinterpret_cast<const float4*>(xrow + kk * 32 + lg * 8);
        float4 f1 = *reinterpret_cast<const float4*>(xrow + kk * 32 + lg * 8 + 4);
        bf16x8 a;
        a[0] = (short)f2bf(f0.x); a[1] = (short)f2bf(f0.y);
        a[2] = (short)f2bf(f0.z); a[3] = (short)f2bf(f0.w);
        a[4] = (short)f2bf(f1.x); a[5] = (short)f2bf(f1.y);
        a[6] = (short)f2bf(f1.z); a[7] = (short)f2bf(f1.w);
        afr[kk] = a;
    }

    for (int ch = 0; ch < 3; ++ch) {
        const bf16x8* bf = reinterpret_cast<const bf16x8*>(frag + (size_t)ch * 2048 * 8);
        f32x4 acc[8];
        #pragma unroll
        for (int n = 0; n < 8; ++n) acc[n] = (f32x4){0.f, 0.f, 0.f, 0.f};
        #pragma unroll
        for (int n = 0; n < 8; ++n)
            #pragma unroll
            for (int kk = 0; kk < 4; ++kk)
                acc[n] = __builtin_amdgcn_mfma_f32_16x16x32_bf16(afr[kk], bf[(n * 4 + kk) * 64 + l],
                                                                 acc[n], 0, 0, 0);
        if (ch < 2) {
            u16* Y = (ch == 0) ? Yq : Yk;
            float bv[8];
            #pragma unroll
            for (int n = 0; n < 8; ++n) bv[n] = bias[ch * 128 + n * 16 + lr];
            #pragma unroll
            for (int reg = 0; reg < 4; ++reg) {
                int r = base + w * 16 + lg * 4 + reg;
                if (r < R) {
                    u16x8 pk;
                    #pragma unroll
                    for (int n = 0; n < 8; ++n) pk[n] = f2bf(acc[n][reg] + bv[n]);
                    *reinterpret_cast<u16x8*>(&Y[(size_t)r * 128 + lr * 8]) = pk;
                }
            }
        } else {
            #pragma unroll
            for (int n = 0; n < 8; ++n) {
                int col = n * 16 + lr;
                float bv = bias[ch * 128 + col];
                #pragma unroll
                for (int reg = 0; reg < 4; ++reg) {
                    int r = base + w * 16 + lg * 4 + reg;
                    if (r < R) Yv[(size_t)r * 128 + col] = f2bf(acc[n][reg] + bv);
                }
            }
        }
    }
}

// ---------- hproj GEMM: BARRIER-FREE, bf16 input, f32 out ----------

__global__ __launch_bounds__(256) void gemm128_bf(
    const u16* __restrict__ X, const short* __restrict__ frag,
    const float* __restrict__ bias, float* __restrict__ Y, int R)
{
    const int t = threadIdx.x;
    const int base = blockIdx.x * 64;
    const int w = t >> 6, l = t & 63, lr = l & 15, lg = l >> 4;

    const int myrow = base + w * 16 + lr;
    const u16* xrow = X + (size_t)(myrow < R ? myrow : (R - 1)) * 128;
    bf16x8 afr[4];
    #pragma unroll
    for (int kk = 0; kk < 4; ++kk)
        afr[kk] = *reinterpret_cast<const bf16x8*>(xrow + kk * 32 + lg * 8);

    const bf16x8* bf = reinterpret_cast<const bf16x8*>(frag);
    f32x4 acc[8];
    #pragma unroll
    for (int n = 0; n < 8; ++n) acc[n] = (f32x4){0.f, 0.f, 0.f, 0.f};
    #pragma unroll
    for (int n = 0; n < 8; ++n)
        #pragma unroll
        for (int kk = 0; kk < 4; ++kk)
            acc[n] = __builtin_amdgcn_mfma_f32_16x16x32_bf16(afr[kk], bf[(n * 4 + kk) * 64 + l],
                                                             acc[n], 0, 0, 0);
    #pragma unroll
    for (int n = 0; n < 8; ++n) {
        int col = n * 16 + lr;
        float bv = bias[col];
        #pragma unroll
        for (int reg = 0; reg < 4; ++reg) {
            int r = base + w * 16 + lg * 4 + reg;
            if (r < R) Y[(size_t)r * 128 + col] = acc[n][reg] + bv;
        }
    }
}

// ---------- fused edge kernel: BARRIER-FREE, per-n GEMM1 (low VGPR) ----------
// Per-n structure: {4 chained MFMAs -> f32x4 acc -> tanh/score epilogue for n}.
// Peak live state: afr(16) + one gather pair(16) + acc(4) + macc(4) -> target
// VGPR <= 64 to cross the 8-waves/SIMD step (m69: waves halve at 64/128).

__global__ __launch_bounds__(256) void edge_mfma(
    const float* __restrict__ e, const int* __restrict__ src, const int* __restrict__ dst,
    const short* __restrict__ cfrag, const float* __restrict__ cbias,
    const short* __restrict__ efrag, const float* __restrict__ ebias,
    const u16* __restrict__ qbh, const u16* __restrict__ kbh,
    float* __restrict__ e_out, float* __restrict__ mean_out,
    float* __restrict__ logit, int E)
{
    __shared__ __align__(16) char lds[64 * 256];
    const int t = threadIdx.x;
    const int base = blockIdx.x * 64;
    const int w = t >> 6, l = t & 63;
    const int lr = l & 15, lg = l >> 4;
    const int rowbase = (w * 16 + lr) * 256;
    const int swz = lr << 4;

    int si[4], di[4];
    #pragma unroll
    for (int reg = 0; reg < 4; ++reg) {
        int ei = base + w * 16 + lg * 4 + reg;
        int ce = ei < E ? ei : (E - 1);
        si[reg] = src[ce];
        di[reg] = dst[ce];
    }
    // gather batch A (heads 0..3)
    u16x4 kA[4], qA[4];
    #pragma unroll
    for (int reg = 0; reg < 4; ++reg) {
        kA[reg] = *reinterpret_cast<const u16x4*>(&kbh[(size_t)si[reg] * 128 + lr * 8]);
        qA[reg] = *reinterpret_cast<const u16x4*>(&qbh[(size_t)di[reg] * 128 + lr * 8]);
    }

    // GEMM1 A-fragments straight from global e (own row), f2bf in-register
    const int myrow = base + w * 16 + lr;
    const float* erow = e + (size_t)(myrow < E ? myrow : (E - 1)) * 128;
    bf16x8 afr[4];
    #pragma unroll
    for (int kk = 0; kk < 4; ++kk) {
        float4 f0 = *reinterpret_cast<const float4*>(erow + kk * 32 + lg * 8);
        float4 f1 = *reinterpret_cast<const float4*>(erow + kk * 32 + lg * 8 + 4);
        bf16x8 a;
        a[0] = (short)f2bf(f0.x); a[1] = (short)f2bf(f0.y);
        a[2] = (short)f2bf(f0.z); a[3] = (short)f2bf(f0.w);
        a[4] = (short)f2bf(f1.x); a[5] = (short)f2bf(f1.y);
        a[6] = (short)f2bf(f1.z); a[7] = (short)f2bf(f1.w);
        afr[kk] = a;
    }

    const bf16x8* cf = reinterpret_cast<const bf16x8*>(cfrag);
    float macc[4] = {0.f, 0.f, 0.f, 0.f};

    // ---- half A: per-n GEMM1 + epilogue (heads 0..3) ----
    #pragma unroll
    for (int n = 0; n < 4; ++n) {
        f32x4 acc = (f32x4){0.f, 0.f, 0.f, 0.f};
        #pragma unroll
        for (int kk = 0; kk < 4; ++kk)
            acc = __builtin_amdgcn_mfma_f32_16x16x32_bf16(afr[kk], cf[(n * 4 + kk) * 64 + l],
                                                          acc, 0, 0, 0);
        const int col = n * 16 + lr;
        const float cb = cbias[col];
        #pragma unroll
        for (int reg = 0; reg < 4; ++reg) {
            float sc = fast_tanh(acc[reg] + cb) * bf2f(kA[reg][n]) * bf2f(qA[reg][n]);
            macc[reg] += sc;
            int row = w * 16 + lg * 4 + reg;
            *reinterpret_cast<u16*>(
                lds + row * 256 + ((col * 2) ^ ((row & 15) << 4))) = f2bf(sc);
        }
    }

    // gather batch B (heads 4..7) — kA/qA dead after half A
    u16x4 kB[4], qB[4];
    #pragma unroll
    for (int reg = 0; reg < 4; ++reg) {
        kB[reg] = *reinterpret_cast<const u16x4*>(&kbh[(size_t)si[reg] * 128 + lr * 8 + 4]);
        qB[reg] = *reinterpret_cast<const u16x4*>(&qbh[(size_t)di[reg] * 128 + lr * 8 + 4]);
    }

    // ---- half B: per-n GEMM1 + epilogue (heads 4..7) ----
    #pragma unroll
    for (int n = 4; n < 8; ++n) {
        f32x4 acc = (f32x4){0.f, 0.f, 0.f, 0.f};
        #pragma unroll
        for (int kk = 0; kk < 4; ++kk)
            acc = __builtin_amdgcn_mfma_f32_16x16x32_bf16(afr[kk], cf[(n * 4 + kk) * 64 + l],
                                                          acc, 0, 0, 0);
        const int col = n * 16 + lr;
        const float cb = cbias[col];
        #pragma unroll
        for (int reg = 0; reg < 4; ++reg) {
            float sc = fast_tanh(acc[reg] + cb) * bf2f(kB[reg][n - 4]) * bf2f(qB[reg][n - 4]);
            macc[reg] += sc;
            int row = w * 16 + lg * 4 + reg;
            *reinterpret_cast<u16*>(
                lds + row * 256 + ((col * 2) ^ ((row & 15) << 4))) = f2bf(sc);
        }
    }
    #pragma unroll
    for (int reg = 0; reg < 4; ++reg) {
        int ei = base + w * 16 + lg * 4 + reg;
        if (ei < E) mean_out[(size_t)ei * 16 + lr] = macc[reg] * 0.125f;
    }

    // A-frags from score (same wave wrote these rows; in-wave ds ordering)
    bf16x8 afr2[4];
    #pragma unroll
    for (int kk = 0; kk < 4; ++kk)
        afr2[kk] = *reinterpret_cast<const bf16x8*>(lds + rowbase + ((kk * 64 + lg * 16) ^ swz));

    // logit via indicator-MFMA: B[k][h] = (k>>4 == h); LINEAR store by edge id
    {
        bf16x8 ind[4];
        #pragma unroll
        for (int kk = 0; kk < 4; ++kk)
            #pragma unroll
            for (int j = 0; j < 8; ++j)
                ind[kk][j] = ((kk * 32 + lg * 8 + j) >> 4 == lr) ? (short)0x3F80 : (short)0;
        f32x4 lac = (f32x4){0.f, 0.f, 0.f, 0.f};
        #pragma unroll
        for (int kk = 0; kk < 4; ++kk)
            lac = __builtin_amdgcn_mfma_f32_16x16x32_bf16(afr2[kk], ind[kk], lac, 0, 0, 0);
        if (lr < 8) {
            #pragma unroll
            for (int reg = 0; reg < 4; ++reg) {
                int ei = base + w * 16 + lg * 4 + reg;
                if (ei < E) logit[(size_t)ei * 8 + lr] = lac[reg] * ATTN_SCALE;
            }
        }
    }

    // GEMM2 per-n: e_out = score @ eproj_w.T -> bf16 -> LDS (own rows)
    const bf16x8* ef = reinterpret_cast<const bf16x8*>(efrag);
    #pragma unroll
    for (int n = 0; n < 8; ++n) {
        f32x4 a2 = (f32x4){0.f, 0.f, 0.f, 0.f};
        #pragma unroll
        for (int kk = 0; kk < 4; ++kk)
            a2 = __builtin_amdgcn_mfma_f32_16x16x32_bf16(afr2[kk], ef[(n * 4 + kk) * 64 + l],
                                                         a2, 0, 0, 0);
        const int col = n * 16 + lr;
        const float eb = ebias[col];
        #pragma unroll
        for (int reg = 0; reg < 4; ++reg) {
            int row = w * 16 + lg * 4 + reg;
            *reinterpret_cast<u16*>(
                lds + row * 256 + ((col * 2) ^ ((row & 15) << 4))) = f2bf(a2[reg] + eb);
        }
    }
    // e_out coalesced stores from own rows (wave-private rows)
    #pragma unroll
    for (int rh = 0; rh < 2; ++rh) {
        #pragma unroll
        for (int ih = 0; ih < 2; ++ih) {
            int row = w * 16 + (l >> 3) + 8 * rh;
            int col = (l & 7) * 8 + 64 * ih;
            bf16x8 sv = *reinterpret_cast<const bf16x8*>(
                lds + row * 256 + ((col * 2) ^ ((row & 15) << 4)));
            float4 o0, o1;
            o0.x = bf2f((u16)sv[0]); o0.y = bf2f((u16)sv[1]);
            o0.z = bf2f((u16)sv[2]); o0.w = bf2f((u16)sv[3]);
            o1.x = bf2f((u16)sv[4]); o1.y = bf2f((u16)sv[5]);
            o1.z = bf2f((u16)sv[6]); o1.w = bf2f((u16)sv[7]);
            if (base + row < E) {
                *reinterpret_cast<float4*>(&e_out[(size_t)(base + row) * 128 + col]) = o0;
                *reinterpret_cast<float4*>(&e_out[(size_t)(base + row) * 128 + col + 4]) = o1;
            }
        }
    }
}

// ---------- per-node softmax + aggregation (hagg out as bf16) ----------

__global__ __launch_bounds__(256) void node_kernel(
    const int* __restrict__ offsets, const int* __restrict__ eidx,
    const int* __restrict__ src, const float* __restrict__ logit,
    const u16* __restrict__ vbh, u16* __restrict__ hagg, int N)
{
    __shared__ int   ls_src[4][64];
    __shared__ float ls_l[4][64][8];
    const int t = threadIdx.x, w = t >> 6, lane = t & 63;
    const int node = blockIdx.x * 4 + w;
    int off = 0, deg = 0;
    if (node < N) { off = offsets[node]; deg = offsets[node + 1] - off; }

    const int h = lane & 7, g = lane >> 3;
    float m = -3.0e38f, s = 0.f;

    for (int c0 = 0; c0 < deg; c0 += 64) {
        int cnt = min(64, deg - c0);
        if (lane < cnt) {
            int eid = eidx[off + c0 + lane];
            ls_src[w][lane] = src[eid];
            float4 l0 = *reinterpret_cast<const float4*>(&logit[(size_t)eid * 8]);
            float4 l1 = *reinterpret_cast<const float4*>(&logit[(size_t)eid * 8 + 4]);
            *reinterpret_cast<float4*>(&ls_l[w][lane][0]) = l0;
            *reinterpret_cast<float4*>(&ls_l[w][lane][4]) = l1;
        }
        __asm__ __volatile__("s_waitcnt lgkmcnt(0)" ::: "memory");
        float cm = -3.0e38f;
        for (int j = g; j < cnt; j += 8) cm = fmaxf(cm, ls_l[w][j][h]);
        cm = fmaxf(cm, __shfl_xor(cm, 8));
        cm = fmaxf(cm, __shfl_xor(cm, 16));
        cm = fmaxf(cm, __shfl_xor(cm, 32));
        float mn = fmaxf(m, cm);
        float cs = 0.f;
        for (int j = g; j < cnt; j += 8) cs += __expf(ls_l[w][j][h] - mn);
        cs += __shfl_xor(cs, 8); cs += __shfl_xor(cs, 16); cs += __shfl_xor(cs, 32);
        s = s * __expf(m - mn) + cs;
        m = mn;
    }
    float inv = (deg > 0) ? 1.f / s : 0.f;

    float a0 = 0.f, a1 = 0.f;
    const int d0 = lane, d1 = lane + 64, h0 = lane >> 4, h1 = 4 + h0;
    for (int c0 = 0; c0 < deg; c0 += 64) {
        int cnt = min(64, deg - c0);
        if (deg > 64 && lane < cnt) {
            int eid = eidx[off + c0 + lane];
            ls_src[w][lane] = src[eid];
            float4 l0 = *reinterpret_cast<const float4*>(&logit[(size_t)eid * 8]);
            float4 l1 = *reinterpret_cast<const float4*>(&logit[(size_t)eid * 8 + 4]);
            *reinterpret_cast<float4*>(&ls_l[w][lane][0]) = l0;
            *reinterpret_cast<float4*>(&ls_l[w][lane][4]) = l1;
        }
        __asm__ __volatile__("s_waitcnt lgkmcnt(0)" ::: "memory");
        for (int j = g; j < cnt; j += 8)
            ls_l[w][j][h] = __expf(ls_l[w][j][h] - m) * inv;
        __asm__ __volatile__("s_waitcnt lgkmcnt(0)" ::: "memory");
        #pragma unroll 4
        for (int j = 0; j < cnt; ++j) {
            int sn = ls_src[w][j];
            float w0 = ls_l[w][j][h0], w1 = ls_l[w][j][h1];
            a0 += w0 * bf2f(vbh[(size_t)sn * 128 + d0]);
            a1 += w1 * bf2f(vbh[(size_t)sn * 128 + d1]);
        }
    }
    if (node < N) {
        hagg[(size_t)node * 128 + d0] = f2bf(a0);
        hagg[(size_t)node * 128 + d1] = f2bf(a1);
    }
}

// ---------- launcher ----------

extern "C" void kernel_launch(void* const* d_in, const int* in_sizes, int n_in,
                              void* d_out, int out_size, void* d_ws, size_t ws_size,
                              hipStream_t stream)
{
    const float* h       = (const float*)d_in[0];
    const float* e       = (const float*)d_in[1];
    const int*   src     = (const int*)d_in[2];
    const int*   dst     = (const int*)d_in[3];
    const float* qkv_w   = (const float*)d_in[4];
    const float* qkv_b   = (const float*)d_in[5];
    const float* c_w     = (const float*)d_in[6];
    const float* c_b     = (const float*)d_in[7];
    const float* hproj_w = (const float*)d_in[8];
    const float* hproj_b = (const float*)d_in[9];
    const float* eproj_w = (const float*)d_in[10];
    const float* eproj_b = (const float*)d_in[11];

    const int N = in_sizes[0] / 128;
    const int E = in_sizes[1] / 128;

    float* h_out    = (float*)d_out;
    float* e_out    = h_out + (size_t)N * 128;
    float* mean_out = e_out + (size_t)E * 128;

    char* wp = (char*)d_ws;
    auto alloc = [&](size_t b) {
        void* p = (void*)wp;
        wp += (b + 255) & ~(size_t)255;
        return p;
    };
    short* fragbuf = (short*)alloc(sizeof(short) * 6 * 2048 * 8);
    u16*   qbh     = (u16*)alloc(sizeof(u16) * (size_t)N * 128);
    u16*   kbh     = (u16*)alloc(sizeof(u16) * (size_t)N * 128);
    u16*   vbh     = (u16*)alloc(sizeof(u16) * (size_t)N * 128);
    u16*   hagg    = (u16*)alloc(sizeof(u16) * (size_t)N * 128);
    float* logit   = (float*)alloc(sizeof(float) * (size_t)E * 8);
    int*   counts  = (int*)alloc(sizeof(int) * (N + 1));
    int*   offs    = (int*)alloc(sizeof(int) * (N + 1));
    int*   cursor  = (int*)alloc(sizeof(int) * (N + 1));
    int*   stmp    = (int*)alloc(sizeof(int) * (N + 1));
    int*   bsum    = (int*)alloc(sizeof(int) * 64);
    int*   eidx    = (int*)alloc(sizeof(int) * E);

    short* qkvfrag = fragbuf;
    short* cfragb  = fragbuf + (size_t)3 * 2048 * 8;
    short* efragb  = fragbuf + (size_t)4 * 2048 * 8;
    short* hpfrag  = fragbuf + (size_t)5 * 2048 * 8;

    hipMemsetAsync(counts, 0, sizeof(int) * (N + 1), stream);

    make_frag6<<<48, 256, 0, stream>>>(qkv_w, qkv_w + 128 * 128, qkv_w + 2 * 128 * 128,
                                       c_w, eproj_w, hproj_w, fragbuf);

    qkv_gemm<<<(N + 63) / 64, 256, 0, stream>>>(h, qkvfrag, qkv_b, qbh, kbh, vbh, N);

    hist_kernel<<<(E + 255) / 256, 256, 0, stream>>>(dst, counts, E);
    int nb = (N + 1023) / 1024;
    scan1<<<nb, 256, 0, stream>>>(counts, stmp, bsum, N);
    scan2<<<1, 64, 0, stream>>>(bsum, nb);
    scan3<<<(N + 255) / 256, 256, 0, stream>>>(stmp, bsum, offs, cursor, N);
    scatter_kernel<<<(E + 255) / 256, 256, 0, stream>>>(dst, cursor, eidx, E);

    edge_mfma<<<(E + 63) / 64, 256, 0, stream>>>(e, src, dst, cfragb, c_b, efragb,
                                                 eproj_b, qbh, kbh, e_out, mean_out, logit, E);

    node_kernel<<<(N + 3) / 4, 256, 0, stream>>>(offs, eidx, src, logit, vbh, hagg, N);

    gemm128_bf<<<(N + 63) / 64, 256, 0, stream>>>(hagg, hpfrag, hproj_b, h_out, N);
}

// Round 14
// 394.593 us; speedup vs baseline: 1.1249x; 1.1249x over previous
//
#include <hip/hip_runtime.h>
#include <cmath>

typedef __attribute__((ext_vector_type(8))) short bf16x8;
typedef __attribute__((ext_vector_type(4))) float f32x4;
typedef __attribute__((ext_vector_type(4))) unsigned short u16x4;
typedef __attribute__((ext_vector_type(8))) unsigned short u16x8;
typedef unsigned short u16;

#define ATTN_SCALE 0.25f

__device__ inline u16 f2bf(float x) {
    union { float f; unsigned u; } v; v.f = x;
    unsigned r = v.u + 0x7FFFu + ((v.u >> 16) & 1u);
    return (u16)(r >> 16);
}
__device__ inline float bf2f(u16 u) {
    union { unsigned u; float f; } v; v.u = ((unsigned)u) << 16; return v.f;
}
__device__ inline float fast_tanh(float x) {
    float xc = fminf(fmaxf(x, -15.f), 15.f);
    float t = __expf(2.f * xc);
    return (t - 1.f) * __builtin_amdgcn_rcpf(t + 1.f);
}

// ---------- CSR build ----------

__global__ __launch_bounds__(256) void hist_kernel(const int* __restrict__ dst,
                                                   int* __restrict__ counts, int E) {
    int i = blockIdx.x * 256 + threadIdx.x;
    if (i < E) atomicAdd(&counts[dst[i]], 1);
}

__global__ __launch_bounds__(256) void scan1(const int* __restrict__ counts,
                                             int* __restrict__ tmp, int* __restrict__ bsum, int N) {
    __shared__ int wsum[4];
    int b = blockIdx.x, t = threadIdx.x;
    int base = b * 1024 + t * 4;
    int v0 = (base + 0 < N) ? counts[base + 0] : 0;
    int v1 = (base + 1 < N) ? counts[base + 1] : 0;
    int v2 = (base + 2 < N) ? counts[base + 2] : 0;
    int v3 = (base + 3 < N) ? counts[base + 3] : 0;
    int p0 = v0, p1 = p0 + v1, p2 = p1 + v2, p3 = p2 + v3;
    int s = p3;
    int lane = t & 63, wid = t >> 6;
    int sc = s;
    #pragma unroll
    for (int d = 1; d < 64; d <<= 1) {
        int o = __shfl_up(sc, d);
        if (lane >= d) sc += o;
    }
    if (lane == 63) wsum[wid] = sc;
    __syncthreads();
    int wof = 0;
    #pragma unroll
    for (int i = 0; i < 4; ++i) if (i < wid) wof += wsum[i];
    int excl = wof + sc - s;
    if (base + 0 < N) tmp[base + 0] = excl + p0;
    if (base + 1 < N) tmp[base + 1] = excl + p1;
    if (base + 2 < N) tmp[base + 2] = excl + p2;
    if (base + 3 < N) tmp[base + 3] = excl + p3;
    if (t == 255) bsum[b] = wof + sc;
}

__global__ void scan2(int* __restrict__ bsum, int nb) {
    int t = threadIdx.x;
    int v = (t < nb) ? bsum[t] : 0;
    int sc = v;
    #pragma unroll
    for (int d = 1; d < 64; d <<= 1) {
        int o = __shfl_up(sc, d);
        if (t >= d) sc += o;
    }
    if (t < nb) bsum[t] = sc - v;
}

__global__ __launch_bounds__(256) void scan3(const int* __restrict__ tmp,
                                             const int* __restrict__ bsum,
                                             int* __restrict__ offsets,
                                             int* __restrict__ cursor, int N) {
    int i = blockIdx.x * 256 + threadIdx.x;
    if (i < N) {
        int v = tmp[i] + bsum[i >> 10];
        offsets[i + 1] = v;
        cursor[i + 1] = v;
    }
    if (i == 0) { offsets[0] = 0; cursor[0] = 0; }
}

__global__ __launch_bounds__(256) void scatter_kernel(const int* __restrict__ dst,
                                                      int* __restrict__ cursor,
                                                      int* __restrict__ eidx, int E) {
    int i = blockIdx.x * 256 + threadIdx.x;
    if (i < E) {
        int p = atomicAdd(&cursor[dst[i]], 1);
        eidx[p] = i;
    }
}

// ---------- 6 weight matrices -> MFMA B-fragments in ONE launch ----------
__global__ __launch_bounds__(256) void make_frag6(
    const float* __restrict__ w0, const float* __restrict__ w1,
    const float* __restrict__ w2, const float* __restrict__ w3,
    const float* __restrict__ w4, const float* __restrict__ w5,
    short* __restrict__ out) {
    int m = blockIdx.x >> 3;
    int id = (blockIdx.x & 7) * 256 + threadIdx.x;
    const float* W = (m == 0) ? w0 : (m == 1) ? w1 : (m == 2) ? w2
                   : (m == 3) ? w3 : (m == 4) ? w4 : w5;
    int l = id & 63, t16 = id >> 6;
    int kk = t16 & 3, n = t16 >> 2;
    int col = n * 16 + (l & 15);
    int k0 = kk * 32 + (l >> 4) * 8;
    short* o = out + (size_t)m * 2048 * 8 + (size_t)id * 8;
    #pragma unroll
    for (int j = 0; j < 8; ++j)
        o[j] = (short)f2bf(W[col * 128 + k0 + j]);
}

// ---------- qkv GEMM: BARRIER-FREE, no LDS ----------

__global__ __launch_bounds__(256) void qkv_gemm(
    const float* __restrict__ X, const short* __restrict__ frag,
    const float* __restrict__ bias,
    u16* __restrict__ Yq, u16* __restrict__ Yk, u16* __restrict__ Yv, int R)
{
    const int t = threadIdx.x;
    const int base = blockIdx.x * 64;
    const int w = t >> 6, l = t & 63, lr = l & 15, lg = l >> 4;

    const int myrow = base + w * 16 + lr;
    const float* xrow = X + (size_t)(myrow < R ? myrow : (R - 1)) * 128;
    bf16x8 afr[4];
    #pragma unroll
    for (int kk = 0; kk < 4; ++kk) {
        f32x4 f0 = *reinterpret_cast<const f32x4*>(xrow + kk * 32 + lg * 8);
        f32x4 f1 = *reinterpret_cast<const f32x4*>(xrow + kk * 32 + lg * 8 + 4);
        bf16x8 a;
        a[0] = (short)f2bf(f0.x); a[1] = (short)f2bf(f0.y);
        a[2] = (short)f2bf(f0.z); a[3] = (short)f2bf(f0.w);
        a[4] = (short)f2bf(f1.x); a[5] = (short)f2bf(f1.y);
        a[6] = (short)f2bf(f1.z); a[7] = (short)f2bf(f1.w);
        afr[kk] = a;
    }

    for (int ch = 0; ch < 3; ++ch) {
        const bf16x8* bf = reinterpret_cast<const bf16x8*>(frag + (size_t)ch * 2048 * 8);
        f32x4 acc[8];
        #pragma unroll
        for (int n = 0; n < 8; ++n) acc[n] = (f32x4){0.f, 0.f, 0.f, 0.f};
        #pragma unroll
        for (int n = 0; n < 8; ++n)
            #pragma unroll
            for (int kk = 0; kk < 4; ++kk)
                acc[n] = __builtin_amdgcn_mfma_f32_16x16x32_bf16(afr[kk], bf[(n * 4 + kk) * 64 + l],
                                                                 acc[n], 0, 0, 0);
        if (ch < 2) {
            u16* Y = (ch == 0) ? Yq : Yk;
            float bv[8];
            #pragma unroll
            for (int n = 0; n < 8; ++n) bv[n] = bias[ch * 128 + n * 16 + lr];
            #pragma unroll
            for (int reg = 0; reg < 4; ++reg) {
                int r = base + w * 16 + lg * 4 + reg;
                if (r < R) {
                    u16x8 pk;
                    #pragma unroll
                    for (int n = 0; n < 8; ++n) pk[n] = f2bf(acc[n][reg] + bv[n]);
                    *reinterpret_cast<u16x8*>(&Y[(size_t)r * 128 + lr * 8]) = pk;
                }
            }
        } else {
            #pragma unroll
            for (int n = 0; n < 8; ++n) {
                int col = n * 16 + lr;
                float bv = bias[ch * 128 + col];
                #pragma unroll
                for (int reg = 0; reg < 4; ++reg) {
                    int r = base + w * 16 + lg * 4 + reg;
                    if (r < R) Yv[(size_t)r * 128 + col] = f2bf(acc[n][reg] + bv);
                }
            }
        }
    }
}

// ---------- hproj GEMM: BARRIER-FREE, bf16 input, f32 out ----------

__global__ __launch_bounds__(256) void gemm128_bf(
    const u16* __restrict__ X, const short* __restrict__ frag,
    const float* __restrict__ bias, float* __restrict__ Y, int R)
{
    const int t = threadIdx.x;
    const int base = blockIdx.x * 64;
    const int w = t >> 6, l = t & 63, lr = l & 15, lg = l >> 4;

    const int myrow = base + w * 16 + lr;
    const u16* xrow = X + (size_t)(myrow < R ? myrow : (R - 1)) * 128;
    bf16x8 afr[4];
    #pragma unroll
    for (int kk = 0; kk < 4; ++kk)
        afr[kk] = *reinterpret_cast<const bf16x8*>(xrow + kk * 32 + lg * 8);

    const bf16x8* bf = reinterpret_cast<const bf16x8*>(frag);
    f32x4 acc[8];
    #pragma unroll
    for (int n = 0; n < 8; ++n) acc[n] = (f32x4){0.f, 0.f, 0.f, 0.f};
    #pragma unroll
    for (int n = 0; n < 8; ++n)
        #pragma unroll
        for (int kk = 0; kk < 4; ++kk)
            acc[n] = __builtin_amdgcn_mfma_f32_16x16x32_bf16(afr[kk], bf[(n * 4 + kk) * 64 + l],
                                                             acc[n], 0, 0, 0);
    #pragma unroll
    for (int n = 0; n < 8; ++n) {
        int col = n * 16 + lr;
        float bv = bias[col];
        #pragma unroll
        for (int reg = 0; reg < 4; ++reg) {
            int r = base + w * 16 + lg * 4 + reg;
            if (r < R) Y[(size_t)r * 128 + col] = acc[n][reg] + bv;
        }
    }
}

// ---------- fused edge kernel: BARRIER-FREE, R11 structure + NT stream hints ----------
// R12 lesson: per-wave ILP > occupancy; 4 independent MFMA chains per half.
// NT loads on e (read once) and NT stores on e_out (written once) keep the
// 656 MB stream out of L2 so q/k gather tables (20 MB) stay L2-hot.
// NT builtins need ext-vector types (f32x4), not HIP_vector_type (R13 fix).

__global__ __launch_bounds__(256) void edge_mfma(
    const float* __restrict__ e, const int* __restrict__ src, const int* __restrict__ dst,
    const short* __restrict__ cfrag, const float* __restrict__ cbias,
    const short* __restrict__ efrag, const float* __restrict__ ebias,
    const u16* __restrict__ qbh, const u16* __restrict__ kbh,
    float* __restrict__ e_out, float* __restrict__ mean_out,
    float* __restrict__ logit, int E)
{
    __shared__ __align__(16) char lds[64 * 256];
    const int t = threadIdx.x;
    const int base = blockIdx.x * 64;
    const int w = t >> 6, l = t & 63;
    const int lr = l & 15, lg = l >> 4;
    const int rowbase = (w * 16 + lr) * 256;
    const int swz = lr << 4;

    int si[4], di[4];
    bool vld[4];
    #pragma unroll
    for (int reg = 0; reg < 4; ++reg) {
        int ei = base + w * 16 + lg * 4 + reg;
        vld[reg] = ei < E;
        int ce = vld[reg] ? ei : (E - 1);
        si[reg] = src[ce];
        di[reg] = dst[ce];
    }
    // gather batch A (heads 0..3): one 8B load per reg per operand
    u16x4 kA[4], qA[4];
    #pragma unroll
    for (int reg = 0; reg < 4; ++reg) {
        kA[reg] = *reinterpret_cast<const u16x4*>(&kbh[(size_t)si[reg] * 128 + lr * 8]);
        qA[reg] = *reinterpret_cast<const u16x4*>(&qbh[(size_t)di[reg] * 128 + lr * 8]);
    }

    // GEMM1 A-fragments straight from global e (own row), NT load + f2bf
    const int myrow = base + w * 16 + lr;
    const float* erow = e + (size_t)(myrow < E ? myrow : (E - 1)) * 128;
    bf16x8 afr[4];
    #pragma unroll
    for (int kk = 0; kk < 4; ++kk) {
        f32x4 f0 = __builtin_nontemporal_load(
            reinterpret_cast<const f32x4*>(erow + kk * 32 + lg * 8));
        f32x4 f1 = __builtin_nontemporal_load(
            reinterpret_cast<const f32x4*>(erow + kk * 32 + lg * 8 + 4));
        bf16x8 a;
        a[0] = (short)f2bf(f0.x); a[1] = (short)f2bf(f0.y);
        a[2] = (short)f2bf(f0.z); a[3] = (short)f2bf(f0.w);
        a[4] = (short)f2bf(f1.x); a[5] = (short)f2bf(f1.y);
        a[6] = (short)f2bf(f1.z); a[7] = (short)f2bf(f1.w);
        afr[kk] = a;
    }

    const bf16x8* cf = reinterpret_cast<const bf16x8*>(cfrag);
    float macc[4] = {0.f, 0.f, 0.f, 0.f};

    // ---- half A: GEMM1 n=0..3 (4 independent chains), epilogue with kA/qA ----
    {
        f32x4 accA[4];
        #pragma unroll
        for (int n = 0; n < 4; ++n) accA[n] = (f32x4){0.f, 0.f, 0.f, 0.f};
        #pragma unroll
        for (int n = 0; n < 4; ++n)
            #pragma unroll
            for (int kk = 0; kk < 4; ++kk)
                accA[n] = __builtin_amdgcn_mfma_f32_16x16x32_bf16(afr[kk], cf[(n * 4 + kk) * 64 + l],
                                                                  accA[n], 0, 0, 0);
        #pragma unroll
        for (int n = 0; n < 4; ++n) {
            const int col = n * 16 + lr;
            const float cb = cbias[col];
            #pragma unroll
            for (int reg = 0; reg < 4; ++reg) {
                float sc = fast_tanh(accA[n][reg] + cb) * bf2f(kA[reg][n]) * bf2f(qA[reg][n]);
                macc[reg] += sc;
                int row = w * 16 + lg * 4 + reg;
                *reinterpret_cast<u16*>(
                    lds + row * 256 + ((col * 2) ^ ((row & 15) << 4))) = f2bf(sc);
            }
        }
    }

    // gather batch B (heads 4..7)
    u16x4 kB[4], qB[4];
    #pragma unroll
    for (int reg = 0; reg < 4; ++reg) {
        kB[reg] = *reinterpret_cast<const u16x4*>(&kbh[(size_t)si[reg] * 128 + lr * 8 + 4]);
        qB[reg] = *reinterpret_cast<const u16x4*>(&qbh[(size_t)di[reg] * 128 + lr * 8 + 4]);
    }

    // ---- half B: GEMM1 n=4..7, epilogue with kB/qB ----
    {
        f32x4 accB[4];
        #pragma unroll
        for (int n = 0; n < 4; ++n) accB[n] = (f32x4){0.f, 0.f, 0.f, 0.f};
        #pragma unroll
        for (int n = 0; n < 4; ++n)
            #pragma unroll
            for (int kk = 0; kk < 4; ++kk)
                accB[n] = __builtin_amdgcn_mfma_f32_16x16x32_bf16(afr[kk], cf[((n + 4) * 4 + kk) * 64 + l],
                                                                  accB[n], 0, 0, 0);
        #pragma unroll
        for (int n = 0; n < 4; ++n) {
            const int col = (n + 4) * 16 + lr;
            const float cb = cbias[col];
            #pragma unroll
            for (int reg = 0; reg < 4; ++reg) {
                float sc = fast_tanh(accB[n][reg] + cb) * bf2f(kB[reg][n]) * bf2f(qB[reg][n]);
                macc[reg] += sc;
                int row = w * 16 + lg * 4 + reg;
                *reinterpret_cast<u16*>(
                    lds + row * 256 + ((col * 2) ^ ((row & 15) << 4))) = f2bf(sc);
            }
        }
    }
    #pragma unroll
    for (int reg = 0; reg < 4; ++reg) {
        int ei = base + w * 16 + lg * 4 + reg;
        if (vld[reg]) mean_out[(size_t)ei * 16 + lr] = macc[reg] * 0.125f;
    }

    // A-frags from score (same wave wrote these rows; in-wave ds ordering)
    bf16x8 afr2[4];
    #pragma unroll
    for (int kk = 0; kk < 4; ++kk)
        afr2[kk] = *reinterpret_cast<const bf16x8*>(lds + rowbase + ((kk * 64 + lg * 16) ^ swz));

    // logit via indicator-MFMA: B[k][h] = (k>>4 == h); LINEAR store by edge id
    {
        bf16x8 ind[4];
        #pragma unroll
        for (int kk = 0; kk < 4; ++kk)
            #pragma unroll
            for (int j = 0; j < 8; ++j)
                ind[kk][j] = ((kk * 32 + lg * 8 + j) >> 4 == lr) ? (short)0x3F80 : (short)0;
        f32x4 lac = (f32x4){0.f, 0.f, 0.f, 0.f};
        #pragma unroll
        for (int kk = 0; kk < 4; ++kk)
            lac = __builtin_amdgcn_mfma_f32_16x16x32_bf16(afr2[kk], ind[kk], lac, 0, 0, 0);
        if (lr < 8) {
            #pragma unroll
            for (int reg = 0; reg < 4; ++reg) {
                int ei = base + w * 16 + lg * 4 + reg;
                if (vld[reg]) logit[(size_t)ei * 8 + lr] = lac[reg] * ATTN_SCALE;
            }
        }
    }

    // GEMM2 per-n: e_out = score @ eproj_w.T -> bf16 -> LDS (own rows)
    const bf16x8* ef = reinterpret_cast<const bf16x8*>(efrag);
    #pragma unroll
    for (int n = 0; n < 8; ++n) {
        f32x4 a2 = (f32x4){0.f, 0.f, 0.f, 0.f};
        #pragma unroll
        for (int kk = 0; kk < 4; ++kk)
            a2 = __builtin_amdgcn_mfma_f32_16x16x32_bf16(afr2[kk], ef[(n * 4 + kk) * 64 + l],
                                                         a2, 0, 0, 0);
        const int col = n * 16 + lr;
        const float eb = ebias[col];
        #pragma unroll
        for (int reg = 0; reg < 4; ++reg) {
            int row = w * 16 + lg * 4 + reg;
            *reinterpret_cast<u16*>(
                lds + row * 256 + ((col * 2) ^ ((row & 15) << 4))) = f2bf(a2[reg] + eb);
        }
    }
    // e_out coalesced NT stores from own rows (wave-private rows)
    #pragma unroll
    for (int rh = 0; rh < 2; ++rh) {
        #pragma unroll
        for (int ih = 0; ih < 2; ++ih) {
            int row = w * 16 + (l >> 3) + 8 * rh;
            int col = (l & 7) * 8 + 64 * ih;
            bf16x8 sv = *reinterpret_cast<const bf16x8*>(
                lds + row * 256 + ((col * 2) ^ ((row & 15) << 4)));
            f32x4 o0, o1;
            o0.x = bf2f((u16)sv[0]); o0.y = bf2f((u16)sv[1]);
            o0.z = bf2f((u16)sv[2]); o0.w = bf2f((u16)sv[3]);
            o1.x = bf2f((u16)sv[4]); o1.y = bf2f((u16)sv[5]);
            o1.z = bf2f((u16)sv[6]); o1.w = bf2f((u16)sv[7]);
            if (base + row < E) {
                __builtin_nontemporal_store(o0,
                    reinterpret_cast<f32x4*>(&e_out[(size_t)(base + row) * 128 + col]));
                __builtin_nontemporal_store(o1,
                    reinterpret_cast<f32x4*>(&e_out[(size_t)(base + row) * 128 + col + 4]));
            }
        }
    }
}

// ---------- per-node softmax + aggregation (hagg out as bf16) ----------

__global__ __launch_bounds__(256) void node_kernel(
    const int* __restrict__ offsets, const int* __restrict__ eidx,
    const int* __restrict__ src, const float* __restrict__ logit,
    const u16* __restrict__ vbh, u16* __restrict__ hagg, int N)
{
    __shared__ int   ls_src[4][64];
    __shared__ float ls_l[4][64][8];
    const int t = threadIdx.x, w = t >> 6, lane = t & 63;
    const int node = blockIdx.x * 4 + w;
    int off = 0, deg = 0;
    if (node < N) { off = offsets[node]; deg = offsets[node + 1] - off; }

    const int h = lane & 7, g = lane >> 3;
    float m = -3.0e38f, s = 0.f;

    for (int c0 = 0; c0 < deg; c0 += 64) {
        int cnt = min(64, deg - c0);
        if (lane < cnt) {
            int eid = eidx[off + c0 + lane];
            ls_src[w][lane] = src[eid];
            float4 l0 = *reinterpret_cast<const float4*>(&logit[(size_t)eid * 8]);
            float4 l1 = *reinterpret_cast<const float4*>(&logit[(size_t)eid * 8 + 4]);
            *reinterpret_cast<float4*>(&ls_l[w][lane][0]) = l0;
            *reinterpret_cast<float4*>(&ls_l[w][lane][4]) = l1;
        }
        __asm__ __volatile__("s_waitcnt lgkmcnt(0)" ::: "memory");
        float cm = -3.0e38f;
        for (int j = g; j < cnt; j += 8) cm = fmaxf(cm, ls_l[w][j][h]);
        cm = fmaxf(cm, __shfl_xor(cm, 8));
        cm = fmaxf(cm, __shfl_xor(cm, 16));
        cm = fmaxf(cm, __shfl_xor(cm, 32));
        float mn = fmaxf(m, cm);
        float cs = 0.f;
        for (int j = g; j < cnt; j += 8) cs += __expf(ls_l[w][j][h] - mn);
        cs += __shfl_xor(cs, 8); cs += __shfl_xor(cs, 16); cs += __shfl_xor(cs, 32);
        s = s * __expf(m - mn) + cs;
        m = mn;
    }
    float inv = (deg > 0) ? 1.f / s : 0.f;

    float a0 = 0.f, a1 = 0.f;
    const int d0 = lane, d1 = lane + 64, h0 = lane >> 4, h1 = 4 + h0;
    for (int c0 = 0; c0 < deg; c0 += 64) {
        int cnt = min(64, deg - c0);
        if (deg > 64 && lane < cnt) {
            int eid = eidx[off + c0 + lane];
            ls_src[w][lane] = src[eid];
            float4 l0 = *reinterpret_cast<const float4*>(&logit[(size_t)eid * 8]);
            float4 l1 = *reinterpret_cast<const float4*>(&logit[(size_t)eid * 8 + 4]);
            *reinterpret_cast<float4*>(&ls_l[w][lane][0]) = l0;
            *reinterpret_cast<float4*>(&ls_l[w][lane][4]) = l1;
        }
        __asm__ __volatile__("s_waitcnt lgkmcnt(0)" ::: "memory");
        for (int j = g; j < cnt; j += 8)
            ls_l[w][j][h] = __expf(ls_l[w][j][h] - m) * inv;
        __asm__ __volatile__("s_waitcnt lgkmcnt(0)" ::: "memory");
        #pragma unroll 4
        for (int j = 0; j < cnt; ++j) {
            int sn = ls_src[w][j];
            float w0 = ls_l[w][j][h0], w1 = ls_l[w][j][h1];
            a0 += w0 * bf2f(vbh[(size_t)sn * 128 + d0]);
            a1 += w1 * bf2f(vbh[(size_t)sn * 128 + d1]);
        }
    }
    if (node < N) {
        hagg[(size_t)node * 128 + d0] = f2bf(a0);
        hagg[(size_t)node * 128 + d1] = f2bf(a1);
    }
}

// ---------- launcher ----------

extern "C" void kernel_launch(void* const* d_in, const int* in_sizes, int n_in,
                              void* d_out, int out_size, void* d_ws, size_t ws_size,
                              hipStream_t stream)
{
    const float* h       = (const float*)d_in[0];
    const float* e       = (const float*)d_in[1];
    const int*   src     = (const int*)d_in[2];
    const int*   dst     = (const int*)d_in[3];
    const float* qkv_w   = (const float*)d_in[4];
    const float* qkv_b   = (const float*)d_in[5];
    const float* c_w     = (const float*)d_in[6];
    const float* c_b     = (const float*)d_in[7];
    const float* hproj_w = (const float*)d_in[8];
    const float* hproj_b = (const float*)d_in[9];
    const float* eproj_w = (const float*)d_in[10];
    const float* eproj_b = (const float*)d_in[11];

    const int N = in_sizes[0] / 128;
    const int E = in_sizes[1] / 128;

    float* h_out    = (float*)d_out;
    float* e_out    = h_out + (size_t)N * 128;
    float* mean_out = e_out + (size_t)E * 128;

    char* wp = (char*)d_ws;
    auto alloc = [&](size_t b) {
        void* p = (void*)wp;
        wp += (b + 255) & ~(size_t)255;
        return p;
    };
    short* fragbuf = (short*)alloc(sizeof(short) * 6 * 2048 * 8);
    u16*   qbh     = (u16*)alloc(sizeof(u16) * (size_t)N * 128);
    u16*   kbh     = (u16*)alloc(sizeof(u16) * (size_t)N * 128);
    u16*   vbh     = (u16*)alloc(sizeof(u16) * (size_t)N * 128);
    u16*   hagg    = (u16*)alloc(sizeof(u16) * (size_t)N * 128);
    float* logit   = (float*)alloc(sizeof(float) * (size_t)E * 8);
    int*   counts  = (int*)alloc(sizeof(int) * (N + 1));
    int*   offs    = (int*)alloc(sizeof(int) * (N + 1));
    int*   cursor  = (int*)alloc(sizeof(int) * (N + 1));
    int*   stmp    = (int*)alloc(sizeof(int) * (N + 1));
    int*   bsum    = (int*)alloc(sizeof(int) * 64);
    int*   eidx    = (int*)alloc(sizeof(int) * E);

    short* qkvfrag = fragbuf;
    short* cfragb  = fragbuf + (size_t)3 * 2048 * 8;
    short* efragb  = fragbuf + (size_t)4 * 2048 * 8;
    short* hpfrag  = fragbuf + (size_t)5 * 2048 * 8;

    hipMemsetAsync(counts, 0, sizeof(int) * (N + 1), stream);

    make_frag6<<<48, 256, 0, stream>>>(qkv_w, qkv_w + 128 * 128, qkv_w + 2 * 128 * 128,
                                       c_w, eproj_w, hproj_w, fragbuf);

    qkv_gemm<<<(N + 63) / 64, 256, 0, stream>>>(h, qkvfrag, qkv_b, qbh, kbh, vbh, N);

    hist_kernel<<<(E + 255) / 256, 256, 0, stream>>>(dst, counts, E);
    int nb = (N + 1023) / 1024;
    scan1<<<nb, 256, 0, stream>>>(counts, stmp, bsum, N);
    scan2<<<1, 64, 0, stream>>>(bsum, nb);
    scan3<<<(N + 255) / 256, 256, 0, stream>>>(stmp, bsum, offs, cursor, N);
    scatter_kernel<<<(E + 255) / 256, 256, 0, stream>>>(dst, cursor, eidx, E);

    edge_mfma<<<(E + 63) / 64, 256, 0, stream>>>(e, src, dst, cfragb, c_b, efragb,
                                                 eproj_b, qbh, kbh, e_out, mean_out, logit, E);

    node_kernel<<<(N + 3) / 4, 256, 0, stream>>>(offs, eidx, src, logit, vbh, hagg, N);

    gemm128_bf<<<(N + 63) / 64, 256, 0, stream>>>(hagg, hpfrag, hproj_b, h_out, N);
}